// Round 2
// baseline (599.562 us; speedup 1.0000x reference)
//
#include <hip/hip_runtime.h>

#define TOK 49
#define DIM 128
#define NHEAD 4
#define NWIN 1024

typedef __bf16 bf16x8 __attribute__((ext_vector_type(8)));
typedef float f32x4 __attribute__((ext_vector_type(4)));
typedef unsigned short u16;
typedef unsigned int u32;

// XOR swizzle within a 128B row: spreads 16-row column reads across banks.
__device__ __forceinline__ int xo128(int row, int kbyte) {
    return row * 128 + (kbyte ^ ((row & 7) << 4));
}
__device__ __forceinline__ int xo256(int row, int kbyte) {
    return row * 256 + (kbyte ^ ((row & 7) << 4));
}
__device__ __forceinline__ bf16x8 cvt8(const float* __restrict__ p) {
    float4 a = *reinterpret_cast<const float4*>(p);
    float4 bq = *reinterpret_cast<const float4*>(p + 4);
    bf16x8 r;
    r[0] = (__bf16)a.x; r[1] = (__bf16)a.y; r[2] = (__bf16)a.z; r[3] = (__bf16)a.w;
    r[4] = (__bf16)bq.x; r[5] = (__bf16)bq.y; r[6] = (__bf16)bq.z; r[7] = (__bf16)bq.w;
    return r;
}
__device__ __forceinline__ u16 bfbits(float x) {
    __bf16 t = (__bf16)x;
    return __builtin_bit_cast(u16, t);
}
__device__ __forceinline__ float bf2f(u16 x) {
    u32 u = ((u32)x) << 16;
    return __builtin_bit_cast(float, u);
}

// Precompute rel-pos bias table [NHEAD][64][64] f32 (zero-padded past 49) into d_ws.
__global__ void bias_pre_kernel(const float* __restrict__ rel, float* __restrict__ biasT) {
    const int idx = blockIdx.x * 256 + threadIdx.x;
    if (idx >= NHEAD * 64 * 64) return;
    const int h = idx >> 12, l = (idx >> 6) & 63, m = idx & 63;
    float v = 0.0f;
    if (l < TOK && m < TOK) {
        const int dl = l / 7 - m / 7 + 6;
        const int dc = l % 7 - m % 7 + 6;
        v = rel[(dl * 13 + dc) * NHEAD + h];
    }
    biasT[idx] = v;
}

__global__ __launch_bounds__(256, 3) void winattn_kernel(
    const float* __restrict__ q, const float* __restrict__ k, const float* __restrict__ v,
    const float* __restrict__ mask, const float* __restrict__ Wq, const float* __restrict__ Wk,
    const float* __restrict__ Wv, const float* __restrict__ Wo, const float* __restrict__ bo,
    const float* __restrict__ biasT, float* __restrict__ out)
{
    __shared__ __align__(16) char lds[49152];
    const int tid = threadIdx.x;
    const int wave = tid >> 6;
    const int lane = tid & 63;
    const int l16 = lane & 15;
    const int k8 = lane >> 4;
    const int b = blockIdx.x;
    const int h = wave;  // wave == head

    char* S  = lds + wave * 8192;  // per-wave [64][64 bf16]: q-slice(cols0-31)|k-slice(cols32-63) -> P
    char* Tm = lds + 32768;        // 16KB: mask bf16 [64][64] -> vt [128 d][64 m] bf16
    char* OH = lds;                // outh [64][128] bf16 (aliases S of waves 0/1 after barrier 3)

    const float* qp = q + (size_t)b * (TOK * DIM);
    const float* kp = k + (size_t)b * (TOK * DIM);
    const float* vp = v + (size_t)b * (TOK * DIM);
    const float* mp = mask + (size_t)(b & (NWIN - 1)) * (TOK * TOK);
    float* op = out + (size_t)b * (TOK * DIM);

    // ---- cooperative: stage shift-mask fp32 -> bf16 LDS (0/-100 exact in bf16) ----
    for (int i = tid; i < TOK * TOK; i += 256) {
        const int l = i / TOK, m = i - l * TOK;
        *reinterpret_cast<u16*>(Tm + xo128(l, m * 2)) = bfbits(mp[i]);
    }

    // ---- projection: A-frags straight from global (row-clamped), B = weight slice ----
    f32x4 acc[4][2];
    auto projg = [&](const float* __restrict__ xp, const float* __restrict__ W) {
        bf16x8 bw[2][4];
        #pragma unroll
        for (int n = 0; n < 2; ++n) {
            const int o = h * 32 + n * 16 + l16;
            #pragma unroll
            for (int kk = 0; kk < 4; ++kk)
                bw[n][kk] = cvt8(W + o * DIM + kk * 32 + k8 * 8);
        }
        #pragma unroll
        for (int mi = 0; mi < 4; ++mi) {
            int row = mi * 16 + l16;
            row = row < TOK ? row : TOK - 1;  // clamp: avoids OOB, masked later
            bf16x8 a[4];
            #pragma unroll
            for (int kk = 0; kk < 4; ++kk)
                a[kk] = cvt8(xp + row * DIM + kk * 32 + k8 * 8);
            #pragma unroll
            for (int n = 0; n < 2; ++n) {
                f32x4 c = {0.f, 0.f, 0.f, 0.f};
                #pragma unroll
                for (int kk = 0; kk < 4; ++kk)
                    c = __builtin_amdgcn_mfma_f32_16x16x32_bf16(a[kk], bw[n][kk], c, 0, 0, 0);
                acc[mi][n] = c;
            }
        }
    };

    // C-frag (row=k8*4+r+16mi token, col=l16+16n dim) -> S[token][colbase+dim]
    auto writeS = [&](int colbase) {
        #pragma unroll
        for (int mi = 0; mi < 4; ++mi) {
            #pragma unroll
            for (int n = 0; n < 2; ++n) {
                const int col = colbase + n * 16 + l16;
                #pragma unroll
                for (int r = 0; r < 4; ++r) {
                    const int row = mi * 16 + k8 * 4 + r;
                    *reinterpret_cast<u16*>(S + xo128(row, col * 2)) = bfbits(acc[mi][n][r]);
                }
            }
        }
    };

    projg(qp, Wq); writeS(0);
    projg(kp, Wk); writeS(32);

    // ---- QK^T swapped: E^T[m][l] over this head's 32 dims (all wave-private) ----
    f32x4 e[4][4];
    {
        bf16x8 ak[4], bq[4];
        #pragma unroll
        for (int mi = 0; mi < 4; ++mi)
            ak[mi] = *reinterpret_cast<const bf16x8*>(S + xo128(mi * 16 + l16, 64 + k8 * 16));
        #pragma unroll
        for (int ni = 0; ni < 4; ++ni)
            bq[ni] = *reinterpret_cast<const bf16x8*>(S + xo128(ni * 16 + l16, k8 * 16));
        #pragma unroll
        for (int mi = 0; mi < 4; ++mi) {
            #pragma unroll
            for (int ni = 0; ni < 4; ++ni) {
                f32x4 c = {0.f, 0.f, 0.f, 0.f};
                e[mi][ni] = __builtin_amdgcn_mfma_f32_16x16x32_bf16(ak[mi], bq[ni], c, 0, 0, 0);
            }
        }
    }

    __syncthreads();  // barrier 1: mask staging visible

    // ---- scale + bias(table, float4) + mask(LDS) + softmax; P -> S (aliases q|k) ----
    {
        const float scale = 0.17677669529663687f;  // 1/sqrt(32)
        #pragma unroll
        for (int ni = 0; ni < 4; ++ni) {
            const int l = ni * 16 + l16;
            const bool lv = l < TOK;
            const float* bgrow = biasT + (h * 64 + l) * 64;
            #pragma unroll
            for (int mi = 0; mi < 4; ++mi) {
                const int m0 = mi * 16 + k8 * 4;
                const float4 bg = *reinterpret_cast<const float4*>(bgrow + m0);
                const uint2 mraw = *reinterpret_cast<const uint2*>(Tm + xo128(l, m0 * 2));
                const float bgv[4] = {bg.x, bg.y, bg.z, bg.w};
                const u16 mkv[4] = {(u16)(mraw.x & 0xffffu), (u16)(mraw.x >> 16),
                                    (u16)(mraw.y & 0xffffu), (u16)(mraw.y >> 16)};
                #pragma unroll
                for (int r = 0; r < 4; ++r) {
                    const int m = m0 + r;
                    float val = -1e30f;
                    if (lv && m < TOK)
                        val = e[mi][ni][r] * scale + bgv[r] + bf2f(mkv[r]);
                    e[mi][ni][r] = val;
                }
            }
            float mx = -1e30f;
            #pragma unroll
            for (int mi = 0; mi < 4; ++mi) {
                #pragma unroll
                for (int r = 0; r < 4; ++r) mx = fmaxf(mx, e[mi][ni][r]);
            }
            mx = fmaxf(mx, __shfl_xor(mx, 16));
            mx = fmaxf(mx, __shfl_xor(mx, 32));
            float s = 0.f;
            #pragma unroll
            for (int mi = 0; mi < 4; ++mi) {
                #pragma unroll
                for (int r = 0; r < 4; ++r) {
                    const float p = __expf(e[mi][ni][r] - mx);
                    e[mi][ni][r] = p;
                    s += p;
                }
            }
            s += __shfl_xor(s, 16);
            s += __shfl_xor(s, 32);
            const float rs = 1.0f / s;
            #pragma unroll
            for (int mi = 0; mi < 4; ++mi) {
                const int m0 = mi * 16 + k8 * 4;
                uint2 pk;
                pk.x = (u32)bfbits(e[mi][ni][0] * rs) | ((u32)bfbits(e[mi][ni][1] * rs) << 16);
                pk.y = (u32)bfbits(e[mi][ni][2] * rs) | ((u32)bfbits(e[mi][ni][3] * rs) << 16);
                *reinterpret_cast<uint2*>(S + xo128(l, m0 * 2)) = pk;
            }
        }
    }

    __syncthreads();  // barrier 2: mask region free -> becomes vt

    // ---- v projection -> vt[d][m] (wave-private rows h*32..h*32+32) ----
    projg(vp, Wv);
    #pragma unroll
    for (int mi = 0; mi < 4; ++mi) {
        #pragma unroll
        for (int n = 0; n < 2; ++n) {
            const int d = h * 32 + n * 16 + l16;
            const int m0 = mi * 16 + k8 * 4;
            uint2 pk;
            pk.x = (u32)bfbits(acc[mi][n][0]) | ((u32)bfbits(acc[mi][n][1]) << 16);
            pk.y = (u32)bfbits(acc[mi][n][2]) | ((u32)bfbits(acc[mi][n][3]) << 16);
            *reinterpret_cast<uint2*>(Tm + xo128(d, m0 * 2)) = pk;
        }
    }

    // ---- PV: out[l][d] = sum_m P[l][m] V[m][d] (wave-private) ----
    f32x4 oacc[4][2];
    {
        bf16x8 bv[2][2];
        #pragma unroll
        for (int n = 0; n < 2; ++n) {
            const int d = h * 32 + n * 16 + l16;
            #pragma unroll
            for (int kk = 0; kk < 2; ++kk)
                bv[n][kk] = *reinterpret_cast<const bf16x8*>(Tm + xo128(d, kk * 64 + k8 * 16));
        }
        #pragma unroll
        for (int mi = 0; mi < 4; ++mi) {
            bf16x8 pa[2];
            #pragma unroll
            for (int kk = 0; kk < 2; ++kk)
                pa[kk] = *reinterpret_cast<const bf16x8*>(S + xo128(mi * 16 + l16, kk * 64 + k8 * 16));
            #pragma unroll
            for (int n = 0; n < 2; ++n) {
                f32x4 c = {0.f, 0.f, 0.f, 0.f};
                c = __builtin_amdgcn_mfma_f32_16x16x32_bf16(pa[0], bv[n][0], c, 0, 0, 0);
                c = __builtin_amdgcn_mfma_f32_16x16x32_bf16(pa[1], bv[n][1], c, 0, 0, 0);
                oacc[mi][n] = c;
            }
        }
    }

    // hoist out-proj weight loads (independent of LDS phases)
    bf16x8 aw[2][4];
    #pragma unroll
    for (int m2 = 0; m2 < 2; ++m2) {
        const int o = (wave * 2 + m2) * 16 + l16;
        #pragma unroll
        for (int kk = 0; kk < 4; ++kk)
            aw[m2][kk] = cvt8(Wo + o * DIM + kk * 32 + k8 * 8);
    }

    __syncthreads();  // barrier 3: all PV reads of S done; OH may overwrite

    // ---- outh[l][dim] bf16 -> OH ----
    #pragma unroll
    for (int mi = 0; mi < 4; ++mi) {
        #pragma unroll
        for (int n = 0; n < 2; ++n) {
            const int col = h * 32 + n * 16 + l16;
            #pragma unroll
            for (int r = 0; r < 4; ++r) {
                const int row = mi * 16 + k8 * 4 + r;
                *reinterpret_cast<u16*>(OH + xo256(row, col * 2)) = bfbits(oacc[mi][n][r]);
            }
        }
    }

    __syncthreads();  // barrier 4

    // ---- output projection, swapped: out^T[o][l]; float4 store + fused bias ----
    {
        #pragma unroll
        for (int ni = 0; ni < 4; ++ni) {
            const int l = ni * 16 + l16;
            bf16x8 bx[4];
            #pragma unroll
            for (int kk = 0; kk < 4; ++kk)
                bx[kk] = *reinterpret_cast<const bf16x8*>(OH + xo256(l, kk * 64 + k8 * 16));
            #pragma unroll
            for (int m2 = 0; m2 < 2; ++m2) {
                f32x4 c = {0.f, 0.f, 0.f, 0.f};
                #pragma unroll
                for (int kk = 0; kk < 4; ++kk)
                    c = __builtin_amdgcn_mfma_f32_16x16x32_bf16(aw[m2][kk], bx[kk], c, 0, 0, 0);
                if (l < TOK) {
                    const int o0 = (wave * 2 + m2) * 16 + k8 * 4;
                    const float4 bias = *reinterpret_cast<const float4*>(bo + o0);
                    float4 st;
                    st.x = c[0] + bias.x;
                    st.y = c[1] + bias.y;
                    st.z = c[2] + bias.z;
                    st.w = c[3] + bias.w;
                    *reinterpret_cast<float4*>(op + l * DIM + o0) = st;
                }
            }
        }
    }
}

extern "C" void kernel_launch(void* const* d_in, const int* in_sizes, int n_in,
                              void* d_out, int out_size, void* d_ws, size_t ws_size,
                              hipStream_t stream) {
    const float* q    = (const float*)d_in[0];
    const float* k    = (const float*)d_in[1];
    const float* v    = (const float*)d_in[2];
    const float* mask = (const float*)d_in[3];
    const float* Wq   = (const float*)d_in[4];
    const float* Wk   = (const float*)d_in[5];
    const float* Wv   = (const float*)d_in[6];
    const float* Wo   = (const float*)d_in[7];
    const float* bo   = (const float*)d_in[8];
    const float* rel  = (const float*)d_in[9];
    float* out = (float*)d_out;
    float* biasT = (float*)d_ws;  // [NHEAD][64][64] f32 = 64 KB

    bias_pre_kernel<<<dim3(64), dim3(256), 0, stream>>>(rel, biasT);

    const int B = in_sizes[0] / (TOK * DIM);  // 8192 windows
    winattn_kernel<<<dim3(B), dim3(256), 0, stream>>>(q, k, v, mask, Wq, Wk, Wv, Wo, bo,
                                                      biasT, out);
}